// Round 1
// baseline (2627.601 us; speedup 1.0000x reference)
//
#include <hip/hip_runtime.h>
#include <hip/hip_bf16.h>

#define G 64
#define KNN 8
#define L 64
#define NEG 0.01f

// ---------------------------------------------------------------------------
// Kernel 1: per-point MLP + scatter-add into grid sums / counts.
// One wave (64 lanes) per point; lane = feature channel l. 4 points / block.
// ---------------------------------------------------------------------------
__global__ __launch_bounds__(256) void point_mlp_scatter(
    const float* __restrict__ pos, const int* __restrict__ pts,
    const float* __restrict__ W1, const float* __restrict__ b1,
    const float* __restrict__ W2, const float* __restrict__ b2,
    const float* __restrict__ Wk1, const float* __restrict__ bk1,
    const float* __restrict__ Wk2, const float* __restrict__ bk2,
    float* __restrict__ sums, float* __restrict__ cnt, int np)
{
    __shared__ float sW2t[16 * 256];          // [j4][l*4 + jj]  (= W2[j][l])
    __shared__ float sW1[3 * 64];
    __shared__ float sb1[64], sb2[64];
    __shared__ float sWk1[64], sbk1[8], sWk2[8], sbk2v[1];
    __shared__ float spos[4][24];
    __shared__ float sh[4][8 * 64];           // per-wave h[k][j]

    const int tid = threadIdx.x;
    for (int i = tid; i < 4096; i += 256) {   // W2 is [j][l] row-major
        int j = i >> 6, l = i & 63;
        sW2t[(j >> 2) * 256 + l * 4 + (j & 3)] = W2[i];
    }
    if (tid < 192) sW1[tid] = W1[tid];
    if (tid < 64) { sb1[tid] = b1[tid]; sb2[tid] = b2[tid]; sWk1[tid] = Wk1[tid]; }
    if (tid < 8)  { sbk1[tid] = bk1[tid]; sWk2[tid] = Wk2[tid]; }
    if (tid == 0) sbk2v[0] = bk2[0];

    const int tp = tid >> 6;        // wave index = local point
    const int l  = tid & 63;        // feature channel
    const int p  = blockIdx.x * 4 + tp;
    const bool active = (p < np);

    if (active && l < 24) spos[tp][l] = pos[p * 24 + l];
    __syncthreads();

    if (active) {
        // h[k][l] = lrelu(pos[k] @ W1 + b1)
        #pragma unroll
        for (int k = 0; k < KNN; ++k) {
            float x0 = spos[tp][k * 3 + 0];
            float x1 = spos[tp][k * 3 + 1];
            float x2 = spos[tp][k * 3 + 2];
            float h = sb1[l] + x0 * sW1[l] + x1 * sW1[64 + l] + x2 * sW1[128 + l];
            sh[tp][k * 64 + l] = (h >= 0.f) ? h : NEG * h;
        }
    }
    __syncthreads();

    if (active) {
        // feat[k][l] = h[k][:] @ W2[:, l] + b2[l]
        float feat[KNN];
        #pragma unroll
        for (int k = 0; k < KNN; ++k) feat[k] = sb2[l];
        for (int j4 = 0; j4 < 16; ++j4) {
            float4 w4 = *(const float4*)&sW2t[j4 * 256 + l * 4];
            #pragma unroll
            for (int k = 0; k < KNN; ++k) {
                float4 h4 = *(const float4*)&sh[tp][k * 64 + j4 * 4];
                feat[k] += h4.x * w4.x + h4.y * w4.y + h4.z * w4.z + h4.w * w4.w;
            }
        }
        // f1[o] = lrelu(Wk1[o,:] @ feat + bk1[o]);  pf = Wk2[0,:] @ f1 + bk2
        float pf = sbk2v[0];
        #pragma unroll
        for (int o = 0; o < KNN; ++o) {
            float a = sbk1[o];
            #pragma unroll
            for (int k = 0; k < KNN; ++k) a += sWk1[o * 8 + k] * feat[k];
            a = (a >= 0.f) ? a : NEG * a;
            pf += sWk2[o] * a;
        }
        int ix = pts[p * 3 + 0], iy = pts[p * 3 + 1], iz = pts[p * 3 + 2];
        int cell = (ix * G + iy) * G + iz;
        atomicAdd(&sums[cell * 64 + l], pf);
        if (l == 0) atomicAdd(&cnt[cell], 1.0f);
    }
}

// ---------------------------------------------------------------------------
// Kernel 2: grid mean (in place): g = cnt>0 ? sums/cnt : 0
// ---------------------------------------------------------------------------
__global__ __launch_bounds__(256) void mean_kernel(
    float* __restrict__ g, const float* __restrict__ cnt)
{
    int t = blockIdx.x * 256 + threadIdx.x;   // over 262144 cells * 16 float4
    int cell = t >> 4, q = t & 15;
    float c = cnt[cell];
    float inv = (c > 0.f) ? 1.f / c : 0.f;
    float4 v = *(float4*)&g[cell * 64 + q * 4];
    v.x *= inv; v.y *= inv; v.z *= inv; v.w *= inv;
    *(float4*)&g[cell * 64 + q * 4] = v;
}

// ---------------------------------------------------------------------------
// Kernel 3: weight transform OIDHW -> [tap][ci/4][co][4] (coalesced float4)
// ---------------------------------------------------------------------------
__global__ __launch_bounds__(256) void transform_w(
    const float* __restrict__ w, float* __restrict__ wT)
{
    int i = blockIdx.x * 256 + threadIdx.x;   // 27*64*64 = 110592
    if (i < 27 * 64 * 64) {
        int tap = i >> 12;
        int r = i & 4095;
        int ci4 = r >> 8;
        int r2 = r & 255;
        int co = r2 >> 2;
        int jj = r2 & 3;
        int ci = ci4 * 4 + jj;
        wT[i] = w[(co * 64 + ci) * 27 + tap];
    }
}

// ---------------------------------------------------------------------------
// Kernel 4: 3D conv 64->64ch, 3x3x3, pad 1, relu(x + b).
// Layout channels-last [z][y][x][c]. Block = 4x4x4 spatial tile, 256 thr:
// thread = (co = tid&63, vz = tid>>6), 16 voxel accumulators.
// ---------------------------------------------------------------------------
__global__ __launch_bounds__(256) void conv3d_relu(
    const float* __restrict__ in, const float* __restrict__ wT,
    const float* __restrict__ bias, float* __restrict__ out)
{
    __shared__ float tile[216 * 64];          // 6x6x6 halo tile, 55 KB

    const int b = blockIdx.x;
    const int tx = b & 15, ty = (b >> 4) & 15, tz = b >> 8;
    const int x0 = tx * 4, y0 = ty * 4, z0 = tz * 4;
    const int tid = threadIdx.x;

    // stage input tile (zero-padded halo)
    for (int i = tid; i < 216 * 16; i += 256) {
        int v = i >> 4, c4 = i & 15;
        int vz = v / 36, rem = v - vz * 36;
        int vy = rem / 6, vx = rem - vy * 6;
        int gz = z0 + vz - 1, gy = y0 + vy - 1, gx = x0 + vx - 1;
        float4 val = make_float4(0.f, 0.f, 0.f, 0.f);
        if ((unsigned)gz < 64u && (unsigned)gy < 64u && (unsigned)gx < 64u)
            val = *(const float4*)&in[(((gz * 64 + gy) * 64 + gx) * 64) + c4 * 4];
        *(float4*)&tile[v * 64 + c4 * 4] = val;
    }
    __syncthreads();

    const int co = tid & 63;
    const int vz = tid >> 6;
    float acc[16];
    #pragma unroll
    for (int v = 0; v < 16; ++v) acc[v] = 0.f;

    for (int dz = 0; dz < 3; ++dz)
    for (int dy = 0; dy < 3; ++dy)
    for (int dx = 0; dx < 3; ++dx) {
        const int tap = (dz * 3 + dy) * 3 + dx;
        const int bv = (vz + dz) * 36 + dy * 6 + dx;
        const float* wrow = wT + tap * 4096 + co * 4;
        for (int c4 = 0; c4 < 16; ++c4) {
            float4 w4 = *(const float4*)&wrow[c4 * 256];
            #pragma unroll
            for (int vy = 0; vy < 4; ++vy) {
                #pragma unroll
                for (int vx = 0; vx < 4; ++vx) {
                    float4 i4 = *(const float4*)&tile[(bv + vy * 6 + vx) * 64 + c4 * 4];
                    acc[vy * 4 + vx] += i4.x * w4.x + i4.y * w4.y + i4.z * w4.z + i4.w * w4.w;
                }
            }
        }
    }

    const float bc = bias[co];
    #pragma unroll
    for (int vy = 0; vy < 4; ++vy) {
        #pragma unroll
        for (int vx = 0; vx < 4; ++vx) {
            float r = acc[vy * 4 + vx] + bc;
            r = (r > 0.f) ? r : 0.f;
            out[(((z0 + vz) * 64 + (y0 + vy)) * 64 + (x0 + vx)) * 64 + co] = r;
        }
    }
}

// ---------------------------------------------------------------------------
extern "C" void kernel_launch(void* const* d_in, const int* in_sizes, int n_in,
                              void* d_out, int out_size, void* d_ws, size_t ws_size,
                              hipStream_t stream)
{
    const float* pos  = (const float*)d_in[0];
    const int*   pts  = (const int*)  d_in[1];
    const float* W1   = (const float*)d_in[2];
    const float* b1   = (const float*)d_in[3];
    const float* W2   = (const float*)d_in[4];
    const float* b2   = (const float*)d_in[5];
    const float* Wk1  = (const float*)d_in[6];
    const float* bk1  = (const float*)d_in[7];
    const float* Wk2  = (const float*)d_in[8];
    const float* bk2  = (const float*)d_in[9];
    const float* Cw1  = (const float*)d_in[10];
    const float* Cb1  = (const float*)d_in[11];
    const float* Cw2  = (const float*)d_in[12];
    const float* Cb2  = (const float*)d_in[13];

    float* out  = (float*)d_out;                       // 64^3 * 64 fp32 = 64 MB
    char*  ws   = (char*)d_ws;
    float* buf0 = (float*)ws;                          // 67108864 B
    float* cntb = (float*)(ws + 67108864);             //  1048576 B
    float* wbuf = (float*)(ws + 68157440);             //   442368 B

    const int np = in_sizes[0] / 24;                   // NP = 150000

    hipMemsetAsync(out,  0, 67108864, stream);         // sums accumulate here
    hipMemsetAsync(cntb, 0, 1048576, stream);

    point_mlp_scatter<<<(np + 3) / 4, 256, 0, stream>>>(
        pos, pts, W1, b1, W2, b2, Wk1, bk1, Wk2, bk2, out, cntb, np);

    mean_kernel<<<16384, 256, 0, stream>>>(out, cntb);

    transform_w<<<432, 256, 0, stream>>>(Cw1, wbuf);
    conv3d_relu<<<4096, 256, 0, stream>>>(out, wbuf, Cb1, buf0);

    transform_w<<<432, 256, 0, stream>>>(Cw2, wbuf);
    conv3d_relu<<<4096, 256, 0, stream>>>(buf0, wbuf, Cb2, out);
}

// Round 2
// 567.393 us; speedup vs baseline: 4.6310x; 4.6310x over previous
//
#include <hip/hip_runtime.h>
#include <hip/hip_bf16.h>
#include <hip/hip_fp16.h>

#define G 64
#define KNN 8
#define NEG 0.01f

typedef _Float16 f16x8 __attribute__((ext_vector_type(8)));
typedef float f32x16 __attribute__((ext_vector_type(16)));

// ---------------------------------------------------------------------------
// Kernel 1: per-point MLP + scatter-add into grid sums / counts. (unchanged)
// ---------------------------------------------------------------------------
__global__ __launch_bounds__(256) void point_mlp_scatter(
    const float* __restrict__ pos, const int* __restrict__ pts,
    const float* __restrict__ W1, const float* __restrict__ b1,
    const float* __restrict__ W2, const float* __restrict__ b2,
    const float* __restrict__ Wk1, const float* __restrict__ bk1,
    const float* __restrict__ Wk2, const float* __restrict__ bk2,
    float* __restrict__ sums, float* __restrict__ cnt, int np)
{
    __shared__ float sW2t[16 * 256];
    __shared__ float sW1[3 * 64];
    __shared__ float sb1[64], sb2[64];
    __shared__ float sWk1[64], sbk1[8], sWk2[8], sbk2v[1];
    __shared__ float spos[4][24];
    __shared__ float sh[4][8 * 64];

    const int tid = threadIdx.x;
    for (int i = tid; i < 4096; i += 256) {
        int j = i >> 6, l = i & 63;
        sW2t[(j >> 2) * 256 + l * 4 + (j & 3)] = W2[i];
    }
    if (tid < 192) sW1[tid] = W1[tid];
    if (tid < 64) { sb1[tid] = b1[tid]; sb2[tid] = b2[tid]; sWk1[tid] = Wk1[tid]; }
    if (tid < 8)  { sbk1[tid] = bk1[tid]; sWk2[tid] = Wk2[tid]; }
    if (tid == 0) sbk2v[0] = bk2[0];

    const int tp = tid >> 6;
    const int l  = tid & 63;
    const int p  = blockIdx.x * 4 + tp;
    const bool active = (p < np);

    if (active && l < 24) spos[tp][l] = pos[p * 24 + l];
    __syncthreads();

    if (active) {
        #pragma unroll
        for (int k = 0; k < KNN; ++k) {
            float x0 = spos[tp][k * 3 + 0];
            float x1 = spos[tp][k * 3 + 1];
            float x2 = spos[tp][k * 3 + 2];
            float h = sb1[l] + x0 * sW1[l] + x1 * sW1[64 + l] + x2 * sW1[128 + l];
            sh[tp][k * 64 + l] = (h >= 0.f) ? h : NEG * h;
        }
    }
    __syncthreads();

    if (active) {
        float feat[KNN];
        #pragma unroll
        for (int k = 0; k < KNN; ++k) feat[k] = sb2[l];
        for (int j4 = 0; j4 < 16; ++j4) {
            float4 w4 = *(const float4*)&sW2t[j4 * 256 + l * 4];
            #pragma unroll
            for (int k = 0; k < KNN; ++k) {
                float4 h4 = *(const float4*)&sh[tp][k * 64 + j4 * 4];
                feat[k] += h4.x * w4.x + h4.y * w4.y + h4.z * w4.z + h4.w * w4.w;
            }
        }
        float pf = sbk2v[0];
        #pragma unroll
        for (int o = 0; o < KNN; ++o) {
            float a = sbk1[o];
            #pragma unroll
            for (int k = 0; k < KNN; ++k) a += sWk1[o * 8 + k] * feat[k];
            a = (a >= 0.f) ? a : NEG * a;
            pf += sWk2[o] * a;
        }
        int ix = pts[p * 3 + 0], iy = pts[p * 3 + 1], iz = pts[p * 3 + 2];
        int cell = (ix * G + iy) * G + iz;
        atomicAdd(&sums[cell * 64 + l], pf);
        if (l == 0) atomicAdd(&cnt[cell], 1.0f);
    }
}

// ---------------------------------------------------------------------------
// Kernel 2: grid mean (in place, fp32): g = cnt>0 ? sums/cnt : 0
// ---------------------------------------------------------------------------
__global__ __launch_bounds__(256) void mean_kernel(
    float* __restrict__ g, const float* __restrict__ cnt)
{
    int t = blockIdx.x * 256 + threadIdx.x;
    int cell = t >> 4, q = t & 15;
    float c = cnt[cell];
    float inv = (c > 0.f) ? 1.f / c : 0.f;
    float4 v = *(float4*)&g[cell * 64 + q * 4];
    v.x *= inv; v.y *= inv; v.z *= inv; v.w *= inv;
    *(float4*)&g[cell * 64 + q * 4] = v;
}

// ---------------------------------------------------------------------------
// Kernel 3: weight transform OIDHW fp32 -> fp16 B-fragment stream.
// o = (((tap*4+ks)*2+nf)*64 + lane)*8 + i
// value = w[co = nf*32+(lane&31)][ci = ks*16+(lane>>5)*8+i][tap]
// ---------------------------------------------------------------------------
__global__ __launch_bounds__(256) void transform_w_fp16(
    const float* __restrict__ w, _Float16* __restrict__ wT)
{
    int o = blockIdx.x * 256 + threadIdx.x;
    if (o < 27 * 4 * 2 * 64 * 8) {
        int i   = o & 7;
        int l   = (o >> 3) & 63;
        int nf  = (o >> 9) & 1;
        int ks  = (o >> 10) & 3;
        int tap = o >> 12;
        int co = nf * 32 + (l & 31);
        int ci = ks * 16 + (l >> 5) * 8 + i;
        wT[o] = (_Float16)w[(co * 64 + ci) * 27 + tap];
    }
}

// ---------------------------------------------------------------------------
// Kernel 4: implicit-GEMM 3D conv via MFMA 32x32x16 f16.
// Block = 8x8x8 voxels, 4 waves; wave = 4 m-tiles(32 vox) x 2 n-tiles(32 co).
// Halo tile 10x10x10x64ci fp16 in 128 KB dynamic LDS, XOR slot-swizzle by hx.
// B-fragments stream from global (L2-resident 221 KB).
// ---------------------------------------------------------------------------
template<int IN_F32, int OUT_F32>
__global__ __launch_bounds__(256, 1) void conv3d_mfma(
    const void* __restrict__ in_, const _Float16* __restrict__ wT,
    const float* __restrict__ bias, void* __restrict__ out_)
{
    extern __shared__ ushort tile[];   // [1000 voxels][64 ci] fp16, swizzled

    const int bx = blockIdx.x;
    const int X0 = (bx & 7) * 8, Y0 = ((bx >> 3) & 7) * 8, Z0 = (bx >> 6) * 8;
    const int tid = threadIdx.x;

    // ---- stage halo tile: chunk = (voxel, slot of 8 ci) ----
    for (int c = tid; c < 8000; c += 256) {
        int vox = c >> 3, slot = c & 7;
        int hz = vox / 100, r0 = vox - hz * 100;
        int hy = r0 / 10, hx = r0 - hy * 10;
        int gz = Z0 + hz - 1, gy = Y0 + hy - 1, gx = X0 + hx - 1;
        int dst = vox * 64 + (((slot ^ hx) & 7) << 3);
        bool ok = ((unsigned)gz < 64u) && ((unsigned)gy < 64u) && ((unsigned)gx < 64u);
        if (IN_F32) {
            float4 a = make_float4(0.f, 0.f, 0.f, 0.f);
            float4 b = make_float4(0.f, 0.f, 0.f, 0.f);
            if (ok) {
                const float4* p = (const float4*)((const float*)in_ +
                    ((size_t)((gz * 64 + gy) * 64 + gx) * 64 + slot * 8));
                a = p[0]; b = p[1];
            }
            f16x8 v = { (_Float16)a.x, (_Float16)a.y, (_Float16)a.z, (_Float16)a.w,
                        (_Float16)b.x, (_Float16)b.y, (_Float16)b.z, (_Float16)b.w };
            *(f16x8*)&tile[dst] = v;
        } else {
            uint4 v = make_uint4(0u, 0u, 0u, 0u);
            if (ok) v = *(const uint4*)((const ushort*)in_ +
                    ((size_t)((gz * 64 + gy) * 64 + gx) * 64 + slot * 8));
            *(uint4*)&tile[dst] = v;
        }
    }
    __syncthreads();

    const int lane = tid & 63;
    const int wv   = tid >> 6;      // wave id: owns vz = {2w, 2w+1}
    const int lr   = lane & 31;
    const int hi   = lane >> 5;

    int base_m[4];
    #pragma unroll
    for (int mt = 0; mt < 4; ++mt)
        base_m[mt] = (2 * wv + (mt >> 1)) * 100 + ((mt & 1) * 4 + (lr >> 3)) * 10 + (lr & 7);

    f32x16 acc[4][2];
    #pragma unroll
    for (int mt = 0; mt < 4; ++mt)
        #pragma unroll
        for (int nf = 0; nf < 2; ++nf)
            #pragma unroll
            for (int q = 0; q < 16; ++q) acc[mt][nf][q] = 0.f;

    const f16x8* wTB = (const f16x8*)wT;

    for (int dz = 0; dz < 3; ++dz)
    for (int dy = 0; dy < 3; ++dy)
    for (int dx = 0; dx < 3; ++dx) {
        const int tap = (dz * 3 + dy) * 3 + dx;
        const int rowoff = dz * 100 + dy * 10 + dx;
        const int sx = ((lr & 7) + dx) & 7;
        const f16x8* wB = wTB + tap * 512 + lane;
        #pragma unroll
        for (int ks = 0; ks < 4; ++ks) {
            f16x8 b0 = wB[(ks * 2 + 0) * 64];
            f16x8 b1 = wB[(ks * 2 + 1) * 64];
            const int sb = ((2 * ks + hi) ^ sx) & 7;
            #pragma unroll
            for (int mt = 0; mt < 4; ++mt) {
                int idx = (base_m[mt] + rowoff) * 64 + (sb << 3);
                f16x8 a = *(const f16x8*)&tile[idx];
                acc[mt][0] = __builtin_amdgcn_mfma_f32_32x32x16_f16(a, b0, acc[mt][0], 0, 0, 0);
                acc[mt][1] = __builtin_amdgcn_mfma_f32_32x32x16_f16(a, b1, acc[mt][1], 0, 0, 0);
            }
        }
    }

    // ---- epilogue: bias + relu, write [z][y][x][co] ----
    const float bv0 = bias[lr], bv1 = bias[32 + lr];
    #pragma unroll
    for (int mt = 0; mt < 4; ++mt) {
        #pragma unroll
        for (int r = 0; r < 16; ++r) {
            int row = (r & 3) + 8 * (r >> 2) + 4 * hi;   // C/D: col=lane&31, row=f(reg,hi)
            int vlw = mt * 32 + row;
            int vz = 2 * wv + (vlw >> 6);
            int rem = vlw & 63;
            int gy = Y0 + (rem >> 3), gx = X0 + (rem & 7), gz = Z0 + vz;
            size_t off = (((size_t)(gz * 64 + gy) * 64 + gx) << 6) + lr;
            float v0 = fmaxf(acc[mt][0][r] + bv0, 0.f);
            float v1 = fmaxf(acc[mt][1][r] + bv1, 0.f);
            if (OUT_F32) {
                ((float*)out_)[off]      = v0;
                ((float*)out_)[off + 32] = v1;
            } else {
                ((_Float16*)out_)[off]      = (_Float16)v0;
                ((_Float16*)out_)[off + 32] = (_Float16)v1;
            }
        }
    }
}

// ---------------------------------------------------------------------------
extern "C" void kernel_launch(void* const* d_in, const int* in_sizes, int n_in,
                              void* d_out, int out_size, void* d_ws, size_t ws_size,
                              hipStream_t stream)
{
    const float* pos  = (const float*)d_in[0];
    const int*   pts  = (const int*)  d_in[1];
    const float* W1   = (const float*)d_in[2];
    const float* b1   = (const float*)d_in[3];
    const float* W2   = (const float*)d_in[4];
    const float* b2   = (const float*)d_in[5];
    const float* Wk1  = (const float*)d_in[6];
    const float* bk1  = (const float*)d_in[7];
    const float* Wk2  = (const float*)d_in[8];
    const float* bk2  = (const float*)d_in[9];
    const float* Cw1  = (const float*)d_in[10];
    const float* Cb1  = (const float*)d_in[11];
    const float* Cw2  = (const float*)d_in[12];
    const float* Cb2  = (const float*)d_in[13];

    float* out = (float*)d_out;                         // sums/grid fp32, then final out
    char*  ws  = (char*)d_ws;
    _Float16* c1out = (_Float16*)ws;                    // [0, 32M): conv1 out fp16
    float*    cntb  = (float*)(ws + 33554432);          // [32M, 33M): counts
    _Float16* wT1   = (_Float16*)(ws + 34603008);       // 221184 B
    _Float16* wT2   = (_Float16*)(ws + 34824192);       // 221184 B

    const int np = in_sizes[0] / 24;

    hipMemsetAsync(out,  0, 67108864, stream);
    hipMemsetAsync(cntb, 0, 1048576, stream);

    transform_w_fp16<<<432, 256, 0, stream>>>(Cw1, wT1);
    transform_w_fp16<<<432, 256, 0, stream>>>(Cw2, wT2);

    point_mlp_scatter<<<(np + 3) / 4, 256, 0, stream>>>(
        pos, pts, W1, b1, W2, b2, Wk1, bk1, Wk2, bk2, out, cntb, np);

    mean_kernel<<<16384, 256, 0, stream>>>(out, cntb);

    conv3d_mfma<1, 0><<<512, 256, 128000, stream>>>((const void*)out, wT1, Cb1, (void*)c1out);
    conv3d_mfma<0, 1><<<512, 256, 128000, stream>>>((const void*)c1out, wT2, Cb2, (void*)out);
}

// Round 3
// 375.700 us; speedup vs baseline: 6.9939x; 1.5102x over previous
//
#include <hip/hip_runtime.h>
#include <hip/hip_bf16.h>
#include <hip/hip_fp16.h>

#define G 64
#define KNN 8
#define NEG 0.01f

typedef _Float16 f16x2 __attribute__((ext_vector_type(2)));
typedef _Float16 f16x8 __attribute__((ext_vector_type(8)));
typedef float f32x16 __attribute__((ext_vector_type(16)));

// ---------------------------------------------------------------------------
// Kernel 1: persistent per-point MLP + scatter-add. One wave per point-slot,
// grid-stride. All weights in registers (W2/Wk1 as fp16 pairs for fdot2).
// h staged per-wave in LDS fp16 (broadcast reads, no barriers).
// ---------------------------------------------------------------------------
__global__ __launch_bounds__(256) void point_mlp_scatter(
    const float* __restrict__ pos, const int* __restrict__ pts,
    const float* __restrict__ W1, const float* __restrict__ b1,
    const float* __restrict__ W2, const float* __restrict__ b2,
    const float* __restrict__ Wk1, const float* __restrict__ bk1,
    const float* __restrict__ Wk2, const float* __restrict__ bk2,
    float* __restrict__ sums, float* __restrict__ cnt, int np, int nwaves)
{
    __shared__ ushort hbuf[4][8 * 64];      // per-wave h[k][j] fp16

    const int tid = threadIdx.x;
    const int wv  = tid >> 6;
    const int l   = tid & 63;

    // ---- per-lane constants (registers) ----
    const float w1r0 = W1[l], w1r1 = W1[64 + l], w1r2 = W1[128 + l];
    const float b1v = b1[l], b2v = b2[l];

    f16x2 w2p[32];                          // W2[2jp..2jp+1][l] as fp16 pair
    #pragma unroll
    for (int jp = 0; jp < 32; ++jp) {
        float a = W2[(2 * jp) * 64 + l];
        float b = W2[(2 * jp + 1) * 64 + l];
        w2p[jp] = f16x2{(_Float16)a, (_Float16)b};
    }

    // ---- wave-uniform constants (scalar loads) ----
    f16x2 wk1p[32];
    #pragma unroll
    for (int o = 0; o < 8; ++o)
        #pragma unroll
        for (int t = 0; t < 4; ++t)
            wk1p[o * 4 + t] = f16x2{(_Float16)Wk1[o * 8 + 2 * t],
                                    (_Float16)Wk1[o * 8 + 2 * t + 1]};
    float bk1v[8], wk2v[8];
    #pragma unroll
    for (int o = 0; o < 8; ++o) { bk1v[o] = bk1[o]; wk2v[o] = Wk2[o]; }
    const float bk2v = bk2[0];

    _Float16* hw = (_Float16*)hbuf[wv];

    for (int p = blockIdx.x * 4 + wv; p < np; p += nwaves) {
        // ---- load pos for this point (24 floats by first 24 lanes) ----
        float ld = 0.f;
        if (l < 24) ld = pos[(size_t)p * 24 + l];

        // ---- layer 1: h[k][l] = lrelu(x @ W1 + b1), store fp16 to LDS ----
        #pragma unroll
        for (int k = 0; k < KNN; ++k) {
            float x0 = __shfl(ld, k * 3 + 0);
            float x1 = __shfl(ld, k * 3 + 1);
            float x2 = __shfl(ld, k * 3 + 2);
            float h = fmaf(x2, w1r2, fmaf(x1, w1r1, fmaf(x0, w1r0, b1v)));
            h = (h >= 0.f) ? h : NEG * h;
            hw[k * 64 + l] = (_Float16)h;
        }

        // ---- layer 2: feat[k] = h[k][:] . W2[:, l] + b2[l]  (fdot2) ----
        float feat[KNN];
        #pragma unroll
        for (int k = 0; k < KNN; ++k) {
            float fk = b2v;
            #pragma unroll
            for (int jc = 0; jc < 8; ++jc) {
                f16x8 hc = *(const f16x8*)&hbuf[wv][k * 64 + jc * 8];
                const f16x2* hp = (const f16x2*)&hc;
                #pragma unroll
                for (int t = 0; t < 4; ++t)
                    fk = __builtin_amdgcn_fdot2(hp[t], w2p[jc * 4 + t], fk, false);
            }
            feat[k] = fk;
        }

        // ---- k-mix: f1 = lrelu(Wk1 @ feat + bk1); pf = Wk2 @ f1 + bk2 ----
        f16x2 fp[4];
        #pragma unroll
        for (int t = 0; t < 4; ++t)
            fp[t] = f16x2{(_Float16)feat[2 * t], (_Float16)feat[2 * t + 1]};
        float pf = bk2v;
        #pragma unroll
        for (int o = 0; o < 8; ++o) {
            float a = bk1v[o];
            #pragma unroll
            for (int t = 0; t < 4; ++t)
                a = __builtin_amdgcn_fdot2(fp[t], wk1p[o * 4 + t], a, false);
            a = (a >= 0.f) ? a : NEG * a;
            pf = fmaf(wk2v[o], a, pf);
        }

        // ---- scatter ----
        int ix = pts[p * 3 + 0], iy = pts[p * 3 + 1], iz = pts[p * 3 + 2];
        int cell = (ix * G + iy) * G + iz;
        atomicAdd(&sums[(size_t)cell * 64 + l], pf);
        if (l == 0) atomicAdd(&cnt[cell], 1.0f);
    }
}

// ---------------------------------------------------------------------------
// Kernel 3: weight transform OIDHW fp32 -> fp16 B-fragment stream.
// o = (((tap*4+ks)*2+nf)*64 + lane)*8 + i
// value = w[co = nf*32+(lane&31)][ci = ks*16+(lane>>5)*8+i][tap]
// ---------------------------------------------------------------------------
__global__ __launch_bounds__(256) void transform_w_fp16(
    const float* __restrict__ w, _Float16* __restrict__ wT)
{
    int o = blockIdx.x * 256 + threadIdx.x;
    if (o < 27 * 4 * 2 * 64 * 8) {
        int i   = o & 7;
        int l   = (o >> 3) & 63;
        int nf  = (o >> 9) & 1;
        int ks  = (o >> 10) & 3;
        int tap = o >> 12;
        int co = nf * 32 + (l & 31);
        int ci = ks * 16 + (l >> 5) * 8 + i;
        wT[o] = (_Float16)w[(co * 64 + ci) * 27 + tap];
    }
}

// ---------------------------------------------------------------------------
// Kernel 4: implicit-GEMM 3D conv via MFMA 32x32x16 f16.
// Block = 8x8x8 voxels, 4 waves; wave = 4 m-tiles(32 vox) x 2 n-tiles(32 co).
// Halo tile 10x10x10x64ci fp16 in 128 KB dynamic LDS, XOR slot-swizzle by hx.
// NORM: divide staged input by cnt (folds the grid-mean into conv1).
// ---------------------------------------------------------------------------
template<int IN_F32, int OUT_F32, int NORM>
__global__ __launch_bounds__(256, 1) void conv3d_mfma(
    const void* __restrict__ in_, const _Float16* __restrict__ wT,
    const float* __restrict__ bias, const float* __restrict__ cntp,
    void* __restrict__ out_)
{
    extern __shared__ ushort tile[];   // [1000 voxels][64 ci] fp16, swizzled

    const int bx = blockIdx.x;
    const int X0 = (bx & 7) * 8, Y0 = ((bx >> 3) & 7) * 8, Z0 = (bx >> 6) * 8;
    const int tid = threadIdx.x;

    // ---- stage halo tile: chunk = (voxel, slot of 8 ci) ----
    for (int c = tid; c < 8000; c += 256) {
        int vox = c >> 3, slot = c & 7;
        int hz = vox / 100, r0 = vox - hz * 100;
        int hy = r0 / 10, hx = r0 - hy * 10;
        int gz = Z0 + hz - 1, gy = Y0 + hy - 1, gx = X0 + hx - 1;
        int dst = vox * 64 + (((slot ^ hx) & 7) << 3);
        bool ok = ((unsigned)gz < 64u) && ((unsigned)gy < 64u) && ((unsigned)gx < 64u);
        if (IN_F32) {
            float4 a = make_float4(0.f, 0.f, 0.f, 0.f);
            float4 b = make_float4(0.f, 0.f, 0.f, 0.f);
            if (ok) {
                const float4* p = (const float4*)((const float*)in_ +
                    ((size_t)((gz * 64 + gy) * 64 + gx) * 64 + slot * 8));
                a = p[0]; b = p[1];
                if (NORM) {
                    float cv = cntp[(gz * 64 + gy) * 64 + gx];
                    float inv = (cv > 0.f) ? 1.f / cv : 0.f;
                    a.x *= inv; a.y *= inv; a.z *= inv; a.w *= inv;
                    b.x *= inv; b.y *= inv; b.z *= inv; b.w *= inv;
                }
            }
            f16x8 v = { (_Float16)a.x, (_Float16)a.y, (_Float16)a.z, (_Float16)a.w,
                        (_Float16)b.x, (_Float16)b.y, (_Float16)b.z, (_Float16)b.w };
            *(f16x8*)&tile[dst] = v;
        } else {
            uint4 v = make_uint4(0u, 0u, 0u, 0u);
            if (ok) v = *(const uint4*)((const ushort*)in_ +
                    ((size_t)((gz * 64 + gy) * 64 + gx) * 64 + slot * 8));
            *(uint4*)&tile[dst] = v;
        }
    }
    __syncthreads();

    const int lane = tid & 63;
    const int wv   = tid >> 6;      // wave id: owns vz = {2w, 2w+1}
    const int lr   = lane & 31;
    const int hi   = lane >> 5;

    int base_m[4];
    #pragma unroll
    for (int mt = 0; mt < 4; ++mt)
        base_m[mt] = (2 * wv + (mt >> 1)) * 100 + ((mt & 1) * 4 + (lr >> 3)) * 10 + (lr & 7);

    f32x16 acc[4][2];
    #pragma unroll
    for (int mt = 0; mt < 4; ++mt)
        #pragma unroll
        for (int nf = 0; nf < 2; ++nf)
            #pragma unroll
            for (int q = 0; q < 16; ++q) acc[mt][nf][q] = 0.f;

    const f16x8* wTB = (const f16x8*)wT;

    for (int dz = 0; dz < 3; ++dz)
    for (int dy = 0; dy < 3; ++dy)
    for (int dx = 0; dx < 3; ++dx) {
        const int tap = (dz * 3 + dy) * 3 + dx;
        const int rowoff = dz * 100 + dy * 10 + dx;
        const int sx = ((lr & 7) + dx) & 7;
        const f16x8* wB = wTB + tap * 512 + lane;
        #pragma unroll
        for (int ks = 0; ks < 4; ++ks) {
            f16x8 b0 = wB[(ks * 2 + 0) * 64];
            f16x8 b1 = wB[(ks * 2 + 1) * 64];
            const int sb = ((2 * ks + hi) ^ sx) & 7;
            #pragma unroll
            for (int mt = 0; mt < 4; ++mt) {
                int idx = (base_m[mt] + rowoff) * 64 + (sb << 3);
                f16x8 a = *(const f16x8*)&tile[idx];
                acc[mt][0] = __builtin_amdgcn_mfma_f32_32x32x16_f16(a, b0, acc[mt][0], 0, 0, 0);
                acc[mt][1] = __builtin_amdgcn_mfma_f32_32x32x16_f16(a, b1, acc[mt][1], 0, 0, 0);
            }
        }
    }

    // ---- epilogue: bias + relu, write [z][y][x][co] ----
    const float bv0 = bias[lr], bv1 = bias[32 + lr];
    #pragma unroll
    for (int mt = 0; mt < 4; ++mt) {
        #pragma unroll
        for (int r = 0; r < 16; ++r) {
            int row = (r & 3) + 8 * (r >> 2) + 4 * hi;   // C/D: col=lane&31, row=f(reg,hi)
            int vlw = mt * 32 + row;
            int vz = 2 * wv + (vlw >> 6);
            int rem = vlw & 63;
            int gy = Y0 + (rem >> 3), gx = X0 + (rem & 7), gz = Z0 + vz;
            size_t off = (((size_t)(gz * 64 + gy) * 64 + gx) << 6) + lr;
            float v0 = fmaxf(acc[mt][0][r] + bv0, 0.f);
            float v1 = fmaxf(acc[mt][1][r] + bv1, 0.f);
            if (OUT_F32) {
                ((float*)out_)[off]      = v0;
                ((float*)out_)[off + 32] = v1;
            } else {
                ((_Float16*)out_)[off]      = (_Float16)v0;
                ((_Float16*)out_)[off + 32] = (_Float16)v1;
            }
        }
    }
}

// ---------------------------------------------------------------------------
extern "C" void kernel_launch(void* const* d_in, const int* in_sizes, int n_in,
                              void* d_out, int out_size, void* d_ws, size_t ws_size,
                              hipStream_t stream)
{
    const float* pos  = (const float*)d_in[0];
    const int*   pts  = (const int*)  d_in[1];
    const float* W1   = (const float*)d_in[2];
    const float* b1   = (const float*)d_in[3];
    const float* W2   = (const float*)d_in[4];
    const float* b2   = (const float*)d_in[5];
    const float* Wk1  = (const float*)d_in[6];
    const float* bk1  = (const float*)d_in[7];
    const float* Wk2  = (const float*)d_in[8];
    const float* bk2  = (const float*)d_in[9];
    const float* Cw1  = (const float*)d_in[10];
    const float* Cb1  = (const float*)d_in[11];
    const float* Cw2  = (const float*)d_in[12];
    const float* Cb2  = (const float*)d_in[13];

    float* out = (float*)d_out;                         // sums grid fp32, then final out
    char*  ws  = (char*)d_ws;
    _Float16* c1out = (_Float16*)ws;                    // [0, 32M): conv1 out fp16
    float*    cntb  = (float*)(ws + 33554432);          // [32M, 33M): counts
    _Float16* wT1   = (_Float16*)(ws + 34603008);       // 221184 B
    _Float16* wT2   = (_Float16*)(ws + 34824192);       // 221184 B

    const int np = in_sizes[0] / 24;

    hipMemsetAsync(out,  0, 67108864, stream);
    hipMemsetAsync(cntb, 0, 1048576, stream);

    transform_w_fp16<<<432, 256, 0, stream>>>(Cw1, wT1);
    transform_w_fp16<<<432, 256, 0, stream>>>(Cw2, wT2);

    const int nblk = 1024;
    point_mlp_scatter<<<nblk, 256, 0, stream>>>(
        pos, pts, W1, b1, W2, b2, Wk1, bk1, Wk2, bk2, out, cntb, np, nblk * 4);

    // conv1 (mean folded in via NORM), conv2
    conv3d_mfma<1, 0, 1><<<512, 256, 128000, stream>>>((const void*)out, wT1, Cb1, cntb, (void*)c1out);
    conv3d_mfma<0, 1, 0><<<512, 256, 128000, stream>>>((const void*)c1out, wT2, Cb2, nullptr, (void*)out);
}

// Round 5
// 325.289 us; speedup vs baseline: 8.0777x; 1.1550x over previous
//
#include <hip/hip_runtime.h>
#include <hip/hip_fp16.h>

#define G 64
#define KNN 8
#define PAD 66

typedef _Float16 f16x2 __attribute__((ext_vector_type(2)));
typedef _Float16 f16x8 __attribute__((ext_vector_type(8)));
typedef float f32x16 __attribute__((ext_vector_type(16)));

static __device__ __forceinline__ f16x2 pkrtz(float a, float b) {
    return __builtin_bit_cast(f16x2, __builtin_amdgcn_cvt_pkrtz(a, b));
}

// ---------------------------------------------------------------------------
// Kernel 1: per-point MLP + scatter. One wave = 4 points per iteration.
// layer1 per-channel fp32 -> swizzled per-wave LDS tile (h: 32 rows x 64 j,
// fp16). layer2 = MFMA 32x32x16 (A = h from LDS, B = W2 in registers).
// k-mix: packed fdot2 + v_permlane32_swap cross-half sum. No barriers.
// ---------------------------------------------------------------------------
__global__ __launch_bounds__(256) void point_mlp_scatter(
    const float* __restrict__ pos, const int* __restrict__ pts,
    const float* __restrict__ W1, const float* __restrict__ b1,
    const float* __restrict__ W2, const float* __restrict__ b2,
    const float* __restrict__ Wk1, const float* __restrict__ bk1,
    const float* __restrict__ Wk2, const float* __restrict__ bk2,
    float* __restrict__ sums, float* __restrict__ cnt, int np, int nslots)
{
    __shared__ _Float16 hb[4 * 2048];     // per-wave 32x64 fp16, slot-swizzled

    const int tid = threadIdx.x;
    const int wv = tid >> 6;
    const int l  = tid & 63;
    const int lr = l & 31;
    const int hi = l >> 5;

    // per-lane constants
    const float w1r0 = W1[l], w1r1 = W1[64 + l], w1r2 = W1[128 + l];
    const float b1v = b1[l];
    const float b2v0 = b2[lr], b2v1 = b2[32 + lr];

    // layer2 B-fragments: B[n][k] = W2[k][n], k = ks*16 + hi*8 + i, n = nf*32+lr
    f16x8 bfr[2][4];
    #pragma unroll
    for (int nf = 0; nf < 2; ++nf)
        #pragma unroll
        for (int ks = 0; ks < 4; ++ks) {
            f16x8 v;
            #pragma unroll
            for (int i = 0; i < 8; ++i)
                v[i] = (_Float16)W2[(ks * 16 + hi * 8 + i) * 64 + nf * 32 + lr];
            bfr[nf][ks] = v;
        }

    // k-mix constants (per-lane k-half: k = 4*hi + {0..3})
    f16x2 wk1a[8], wk1b[8];
    float bk1v[8];
    #pragma unroll
    for (int o = 0; o < 8; ++o) {
        wk1a[o] = f16x2{(_Float16)Wk1[o * 8 + 4 * hi + 0], (_Float16)Wk1[o * 8 + 4 * hi + 1]};
        wk1b[o] = f16x2{(_Float16)Wk1[o * 8 + 4 * hi + 2], (_Float16)Wk1[o * 8 + 4 * hi + 3]};
        bk1v[o] = bk1[o];
    }
    f16x2 wk2p[4];
    #pragma unroll
    for (int j = 0; j < 4; ++j)
        wk2p[j] = f16x2{(_Float16)Wk2[2 * j], (_Float16)Wk2[2 * j + 1]};
    const float bk2v = bk2[0];

    _Float16* hw = hb + wv * 2048;
    const int r7 = lr & 7;

    const int ngrp = (np + 3) >> 2;
    for (int g = blockIdx.x * 4 + wv; g < ngrp; g += nslots) {
        const int gu = __builtin_amdgcn_readfirstlane(g);
        const int p0 = gu * 4;

        // ---- layer1: h[row=pl*8+kk][j=l] = lrelu(pos@W1+b1), swizzled LDS ----
        #pragma unroll
        for (int pl = 0; pl < 4; ++pl) {
            const float* pp = pos + (size_t)((p0 + pl < np) ? (p0 + pl) : (np - 1)) * 24;
            #pragma unroll
            for (int kk = 0; kk < KNN; ++kk) {
                const int row = pl * 8 + kk;
                float x0 = pp[kk * 3 + 0], x1 = pp[kk * 3 + 1], x2 = pp[kk * 3 + 2];
                float h = fmaf(x2, w1r2, fmaf(x1, w1r1, fmaf(x0, w1r0, b1v)));
                h = fmaxf(h, 0.01f * h);
                hw[row * 64 + (l ^ ((row & 7) << 3))] = (_Float16)h;
            }
        }

        // ---- layer2: A-frags from LDS, 8 MFMA ----
        f16x8 a[4];
        #pragma unroll
        for (int ks = 0; ks < 4; ++ks)
            a[ks] = *(const f16x8*)&hw[lr * 64 + (((ks * 2 + hi) ^ r7) << 3)];

        f32x16 acc0, acc1;
        #pragma unroll
        for (int q = 0; q < 16; ++q) { acc0[q] = 0.f; acc1[q] = 0.f; }
        #pragma unroll
        for (int ks = 0; ks < 4; ++ks) {
            acc0 = __builtin_amdgcn_mfma_f32_32x32x16_f16(a[ks], bfr[0][ks], acc0, 0, 0, 0);
            acc1 = __builtin_amdgcn_mfma_f32_32x32x16_f16(a[ks], bfr[1][ks], acc1, 0, 0, 0);
        }
        #pragma unroll
        for (int q = 0; q < 16; ++q) { acc0[q] += b2v0; acc1[q] += b2v1; }

        // ---- k-mix: feat rows per lane: point pl, k = 4*hi + t (t=0..3) ----
        float pf0[4], pf1[4];
        #pragma unroll
        for (int pl = 0; pl < 4; ++pl) {
            f16x2 fA0 = pkrtz(acc0[pl * 4 + 0], acc0[pl * 4 + 1]);
            f16x2 fB0 = pkrtz(acc0[pl * 4 + 2], acc0[pl * 4 + 3]);
            f16x2 fA1 = pkrtz(acc1[pl * 4 + 0], acc1[pl * 4 + 1]);
            f16x2 fB1 = pkrtz(acc1[pl * 4 + 2], acc1[pl * 4 + 3]);
            float f1a[8], f1b[8];
            #pragma unroll
            for (int o = 0; o < 8; ++o) {
                float pa = __builtin_amdgcn_fdot2(fB0, wk1b[o],
                            __builtin_amdgcn_fdot2(fA0, wk1a[o], 0.f, false), false);
                float pb = __builtin_amdgcn_fdot2(fB1, wk1b[o],
                            __builtin_amdgcn_fdot2(fA1, wk1a[o], 0.f, false), false);
                // cross-half sum: after swap, (x + y) = lo-partial + hi-partial
                float xa = pa, ya = pa;
                asm("v_permlane32_swap_b32 %0, %1" : "+v"(xa), "+v"(ya));
                float sa = xa + ya + bk1v[o];
                float xb = pb, yb = pb;
                asm("v_permlane32_swap_b32 %0, %1" : "+v"(xb), "+v"(yb));
                float sb = xb + yb + bk1v[o];
                f1a[o] = fmaxf(sa, 0.01f * sa);
                f1b[o] = fmaxf(sb, 0.01f * sb);
            }
            float s0 = bk2v, s1 = bk2v;
            #pragma unroll
            for (int j = 0; j < 4; ++j) {
                s0 = __builtin_amdgcn_fdot2(pkrtz(f1a[2 * j], f1a[2 * j + 1]), wk2p[j], s0, false);
                s1 = __builtin_amdgcn_fdot2(pkrtz(f1b[2 * j], f1b[2 * j + 1]), wk2p[j], s1, false);
            }
            pf0[pl] = s0; pf1[pl] = s1;
        }

        // ---- scatter: lane writes channel l (hi picks nf-half) ----
        const int* pq = pts + (size_t)p0 * 3;
        #pragma unroll
        for (int pl = 0; pl < 4; ++pl) {
            if (p0 + pl < np) {
                int cell = (pq[pl * 3 + 0] * G + pq[pl * 3 + 1]) * G + pq[pl * 3 + 2];
                float val = hi ? pf1[pl] : pf0[pl];
                atomicAdd(&sums[(size_t)cell * 64 + l], val);
                if (l == 0) atomicAdd(&cnt[cell], 1.0f);
            }
        }
    }
}

// ---------------------------------------------------------------------------
// Kernel 2: fused mean + fp32->fp16 convert into zero-padded 66^3 grid.
// ---------------------------------------------------------------------------
__global__ __launch_bounds__(256) void convert_pad(
    const float* __restrict__ sums, const float* __restrict__ cnt,
    _Float16* __restrict__ gpad)
{
    int t = blockIdx.x * 256 + threadIdx.x;
    if (t >= PAD * PAD * PAD * 8) return;
    int slot = t & 7;
    int cell = t >> 3;
    int x = cell % PAD; int r = cell / PAD; int y = r % PAD; int z = r / PAD;
    f16x8 v;
    #pragma unroll
    for (int i = 0; i < 8; ++i) v[i] = (_Float16)0.f;
    if (x >= 1 && x <= G && y >= 1 && y <= G && z >= 1 && z <= G) {
        int src = ((z - 1) * G + (y - 1)) * G + (x - 1);
        float c = cnt[src];
        float inv = (c > 0.f) ? 1.f / c : 0.f;
        const float4* p = (const float4*)&sums[(size_t)src * 64 + slot * 8];
        float4 a = p[0], b = p[1];
        v = f16x8{(_Float16)(a.x * inv), (_Float16)(a.y * inv), (_Float16)(a.z * inv), (_Float16)(a.w * inv),
                  (_Float16)(b.x * inv), (_Float16)(b.y * inv), (_Float16)(b.z * inv), (_Float16)(b.w * inv)};
    }
    *(f16x8*)&gpad[(size_t)cell * 64 + slot * 8] = v;
}

// ---------------------------------------------------------------------------
// Kernel 2b: zero the border of a padded fp16 grid (for conv1's output).
// ---------------------------------------------------------------------------
__global__ __launch_bounds__(256) void zero_border(_Float16* __restrict__ p)
{
    int t = blockIdx.x * 256 + threadIdx.x;
    if (t >= PAD * PAD * PAD * 8) return;
    int slot = t & 7;
    int cell = t >> 3;
    int x = cell % PAD; int r = cell / PAD; int y = r % PAD; int z = r / PAD;
    if (x >= 1 && x <= G && y >= 1 && y <= G && z >= 1 && z <= G) return;
    f16x8 v;
    #pragma unroll
    for (int i = 0; i < 8; ++i) v[i] = (_Float16)0.f;
    *(f16x8*)&p[(size_t)cell * 64 + slot * 8] = v;
}

// ---------------------------------------------------------------------------
// Kernel 3: weight transform OIDHW fp32 -> fp16 B-fragment stream. (unchanged)
// ---------------------------------------------------------------------------
__global__ __launch_bounds__(256) void transform_w_fp16(
    const float* __restrict__ w, _Float16* __restrict__ wT)
{
    int o = blockIdx.x * 256 + threadIdx.x;
    if (o < 27 * 4 * 2 * 64 * 8) {
        int i   = o & 7;
        int l   = (o >> 3) & 63;
        int nf  = (o >> 9) & 1;
        int ks  = (o >> 10) & 3;
        int tap = o >> 12;
        int co = nf * 32 + (l & 31);
        int ci = ks * 16 + (l >> 5) * 8 + i;
        wT[o] = (_Float16)w[(co * 64 + ci) * 27 + tap];
    }
}

// ---------------------------------------------------------------------------
// Kernel 4: implicit-GEMM conv, A streamed DIRECT from padded global fp16
// (L2/L3-resident), no LDS, no barriers. Block = 8x8x8 tile, 4 waves,
// wave = 4 mt x 2 nf; z-plane rolling window reuses A across (mt>>1, dz).
// XCD z-slab block swizzle. OUT_PAD: write padded fp16, else dense fp32.
// ---------------------------------------------------------------------------
template<int OUT_PAD>
__global__ __launch_bounds__(256) void conv3d_mfma_g(
    const _Float16* __restrict__ in, const _Float16* __restrict__ wT,
    const float* __restrict__ bias, void* __restrict__ out_)
{
    const int lb = blockIdx.x;
    const int bx = (lb & 7) * 64 + (lb >> 3);       // same z-slab -> same XCD
    const int X0 = (bx & 7) * 8, Y0 = ((bx >> 3) & 7) * 8, Z0 = (bx >> 6) * 8;
    const int tid = threadIdx.x;
    const int lane = tid & 63;
    const int wv = tid >> 6;
    const int lr = lane & 31;
    const int hi = lane >> 5;
    const int oxl = lr & 7, oyl = lr >> 3;

    f32x16 acc[4][2];
    #pragma unroll
    for (int mt = 0; mt < 4; ++mt)
        #pragma unroll
        for (int nf = 0; nf < 2; ++nf)
            #pragma unroll
            for (int q = 0; q < 16; ++q) acc[mt][nf][q] = 0.f;

    const f16x8* wTB = (const f16x8*)wT;

    #pragma unroll
    for (int dy = 0; dy < 3; ++dy)
    #pragma unroll
    for (int dx = 0; dx < 3; ++dx) {
        // rolling A window: planes pz4 = dz..dz+1 live in slot (pz4 & 1)
        f16x8 A[2][2][4];                           // [yg][slot][ks]
        #pragma unroll
        for (int yg = 0; yg < 2; ++yg)
            #pragma unroll
            for (int w = 0; w < 2; ++w) {
                size_t base = ((size_t)(((Z0 + 2 * wv + w) * PAD + (Y0 + yg * 4 + oyl + dy)) * PAD
                                        + (X0 + oxl + dx))) * 64 + hi * 8;
                #pragma unroll
                for (int ks = 0; ks < 4; ++ks)
                    A[yg][w][ks] = *(const f16x8*)&in[base + ks * 16];
            }
        #pragma unroll
        for (int dz = 0; dz < 3; ++dz) {
            const int tap = (dz * 3 + dy) * 3 + dx;
            const f16x8* wB = wTB + tap * 512 + lane;
            f16x8 B0[4], B1[4];
            #pragma unroll
            for (int ks = 0; ks < 4; ++ks) {
                B0[ks] = wB[(ks * 2 + 0) * 64];
                B1[ks] = wB[(ks * 2 + 1) * 64];
            }
            #pragma unroll
            for (int zo = 0; zo < 2; ++zo)
                #pragma unroll
                for (int yg = 0; yg < 2; ++yg) {
                    const int win = (dz + zo) & 1;
                    const int mt = 2 * zo + yg;
                    #pragma unroll
                    for (int ks = 0; ks < 4; ++ks) {
                        acc[mt][0] = __builtin_amdgcn_mfma_f32_32x32x16_f16(A[yg][win][ks], B0[ks], acc[mt][0], 0, 0, 0);
                        acc[mt][1] = __builtin_amdgcn_mfma_f32_32x32x16_f16(A[yg][win][ks], B1[ks], acc[mt][1], 0, 0, 0);
                    }
                }
            if (dz < 2) {
                #pragma unroll
                for (int yg = 0; yg < 2; ++yg) {
                    size_t base = ((size_t)(((Z0 + 2 * wv + dz + 2) * PAD + (Y0 + yg * 4 + oyl + dy)) * PAD
                                            + (X0 + oxl + dx))) * 64 + hi * 8;
                    #pragma unroll
                    for (int ks = 0; ks < 4; ++ks)
                        A[yg][dz & 1][ks] = *(const f16x8*)&in[base + ks * 16];
                }
            }
        }
    }

    // ---- epilogue: bias + relu ----
    const float bv0 = bias[lr], bv1 = bias[32 + lr];
    #pragma unroll
    for (int mt = 0; mt < 4; ++mt) {
        #pragma unroll
        for (int r = 0; r < 16; ++r) {
            int row = (r & 3) + 8 * (r >> 2) + 4 * hi;
            int vlw = mt * 32 + row;
            int vz = 2 * wv + (vlw >> 6);
            int rem = vlw & 63;
            int gy = Y0 + (rem >> 3), gx = X0 + (rem & 7), gz = Z0 + vz;
            float v0 = fmaxf(acc[mt][0][r] + bv0, 0.f);
            float v1 = fmaxf(acc[mt][1][r] + bv1, 0.f);
            if (OUT_PAD) {
                size_t off = ((size_t)(((gz + 1) * PAD + (gy + 1)) * PAD + (gx + 1))) * 64 + lr;
                ((_Float16*)out_)[off] = (_Float16)v0;
                ((_Float16*)out_)[off + 32] = (_Float16)v1;
            } else {
                size_t off = (((size_t)(gz * 64 + gy) * 64 + gx) << 6) + lr;
                ((float*)out_)[off] = v0;
                ((float*)out_)[off + 32] = v1;
            }
        }
    }
}

// ---------------------------------------------------------------------------
extern "C" void kernel_launch(void* const* d_in, const int* in_sizes, int n_in,
                              void* d_out, int out_size, void* d_ws, size_t ws_size,
                              hipStream_t stream)
{
    const float* pos  = (const float*)d_in[0];
    const int*   pts  = (const int*)  d_in[1];
    const float* W1   = (const float*)d_in[2];
    const float* b1   = (const float*)d_in[3];
    const float* W2   = (const float*)d_in[4];
    const float* b2   = (const float*)d_in[5];
    const float* Wk1  = (const float*)d_in[6];
    const float* bk1  = (const float*)d_in[7];
    const float* Wk2  = (const float*)d_in[8];
    const float* bk2  = (const float*)d_in[9];
    const float* Cw1  = (const float*)d_in[10];
    const float* Cb1  = (const float*)d_in[11];
    const float* Cw2  = (const float*)d_in[12];
    const float* Cb2  = (const float*)d_in[13];

    float* out = (float*)d_out;                     // fp32 sums, then final out
    char*  ws  = (char*)d_ws;
    const size_t PADB = (size_t)PAD * PAD * PAD * 64 * 2;   // 36,799,488 B
    _Float16* gpad  = (_Float16*)ws;
    _Float16* c1pad = (_Float16*)(ws + PADB);
    float*    cntb  = (float*)(ws + 2 * PADB);
    _Float16* wT1   = (_Float16*)(ws + 2 * PADB + 1048576);
    _Float16* wT2   = (_Float16*)(ws + 2 * PADB + 1048576 + 221184);

    const int np = in_sizes[0] / 24;

    (void)hipMemsetAsync(out,  0, 67108864, stream);      // sums accumulate here
    (void)hipMemsetAsync(cntb, 0, 1048576, stream);

    transform_w_fp16<<<432, 256, 0, stream>>>(Cw1, wT1);
    transform_w_fp16<<<432, 256, 0, stream>>>(Cw2, wT2);

    const int nblk = 2048;
    point_mlp_scatter<<<nblk, 256, 0, stream>>>(
        pos, pts, W1, b1, W2, b2, Wk1, bk1, Wk2, bk2, out, cntb, np, nblk * 4);

    const int padthr = PAD * PAD * PAD * 8;
    convert_pad<<<(padthr + 255) / 256, 256, 0, stream>>>(out, cntb, gpad);
    zero_border<<<(padthr + 255) / 256, 256, 0, stream>>>(c1pad);

    conv3d_mfma_g<1><<<512, 256, 0, stream>>>(gpad, wT1, Cb1, (void*)c1pad);
    conv3d_mfma_g<0><<<512, 256, 0, stream>>>(c1pad, wT2, Cb2, (void*)out);
}

// Round 6
// 259.517 us; speedup vs baseline: 10.1250x; 1.2534x over previous
//
#include <hip/hip_runtime.h>
#include <hip/hip_fp16.h>

#define G 64
#define KNN 8

typedef _Float16 f16x2 __attribute__((ext_vector_type(2)));
typedef _Float16 f16x8 __attribute__((ext_vector_type(8)));
typedef float f32x16 __attribute__((ext_vector_type(16)));

static __device__ __forceinline__ f16x2 pkrtz(float a, float b) {
    return __builtin_bit_cast(f16x2, __builtin_amdgcn_cvt_pkrtz(a, b));
}
static __device__ __forceinline__ void plswap(f16x2& a, f16x2& b) {
    int ai = __builtin_bit_cast(int, a), bi = __builtin_bit_cast(int, b);
    asm("v_permlane32_swap_b32 %0, %1" : "+v"(ai), "+v"(bi));
    a = __builtin_bit_cast(f16x2, ai);
    b = __builtin_bit_cast(f16x2, bi);
}

// ---------------------------------------------------------------------------
// Kernel 1: per-point MLP + scatter. One wave = 4 points per iteration.
// layer1 fp32 -> swizzled per-wave LDS tile; layer2 = MFMA 32x32x16.
// k-mix: permlane32_swap redistributes so each lane owns ONE channel's full
// 8-k feat (no redundant work); orientation resolved by a one-time probe.
// ---------------------------------------------------------------------------
__global__ __launch_bounds__(256) void point_mlp_scatter(
    const float* __restrict__ pos, const int* __restrict__ pts,
    const float* __restrict__ W1, const float* __restrict__ b1,
    const float* __restrict__ W2, const float* __restrict__ b2,
    const float* __restrict__ Wk1, const float* __restrict__ bk1,
    const float* __restrict__ Wk2, const float* __restrict__ bk2,
    float* __restrict__ sums, float* __restrict__ cnt, int np, int nslots)
{
    __shared__ _Float16 hb[4 * 2048];     // per-wave 32x64 fp16, slot-swizzled

    const int tid = threadIdx.x;
    const int wv = tid >> 6;
    const int l  = tid & 63;
    const int lr = l & 31;
    const int hi = l >> 5;

    // ---- orientation probe for v_permlane32_swap_b32 (one-time) ----
    // xp starts as hi (0|1), yp as 2+hi (2|3). After swap, xp tells which
    // source register this lane's "x" output came from.
    int xp = hi, yp = 2 + hi;
    asm("v_permlane32_swap_b32 %0, %1" : "+v"(xp), "+v"(yp));
    const int chan = lr + ((xp & 2) ? 32 : 0);     // set0 -> lr, set1 -> 32+lr
    const int rot = (__builtin_amdgcn_readfirstlane(xp) != 0);  // kpair rotation

    // per-lane constants
    const float w1r0 = W1[l], w1r1 = W1[64 + l], w1r2 = W1[128 + l];
    const float b1v = b1[l];
    const float b2v0 = b2[lr], b2v1 = b2[32 + lr];

    // layer2 B-fragments: B[n][k] = W2[k][n], k = ks*16 + hi*8 + i, n = nf*32+lr
    f16x8 bfr[2][4];
    #pragma unroll
    for (int nf = 0; nf < 2; ++nf)
        #pragma unroll
        for (int ks = 0; ks < 4; ++ks) {
            f16x8 v;
            #pragma unroll
            for (int i = 0; i < 8; ++i)
                v[i] = (_Float16)W2[(ks * 16 + hi * 8 + i) * 64 + nf * 32 + lr];
            bfr[nf][ks] = v;
        }

    // k-mix constants: full-k Wk1 pairs (wave-uniform)
    f16x2 wk1p[32];
    float bk1v[8];
    #pragma unroll
    for (int o = 0; o < 8; ++o) {
        #pragma unroll
        for (int j = 0; j < 4; ++j)
            wk1p[o * 4 + j] = f16x2{(_Float16)Wk1[o * 8 + 2 * j],
                                    (_Float16)Wk1[o * 8 + 2 * j + 1]};
        bk1v[o] = bk1[o];
    }
    f16x2 wk2p[4];
    #pragma unroll
    for (int j = 0; j < 4; ++j)
        wk2p[j] = f16x2{(_Float16)Wk2[2 * j], (_Float16)Wk2[2 * j + 1]};
    const float bk2v = bk2[0];

    _Float16* hw = hb + wv * 2048;
    const int r7 = lr & 7;

    const int ngrp = (np + 3) >> 2;
    for (int g = blockIdx.x * 4 + wv; g < ngrp; g += nslots) {
        const int gu = __builtin_amdgcn_readfirstlane(g);
        const int p0 = gu * 4;

        // ---- layer1: h[row=pl*8+kk][j=l] = lrelu(pos@W1+b1), swizzled LDS ----
        #pragma unroll
        for (int pl = 0; pl < 4; ++pl) {
            const float* pp = pos + (size_t)((p0 + pl < np) ? (p0 + pl) : (np - 1)) * 24;
            #pragma unroll
            for (int kk = 0; kk < KNN; ++kk) {
                const int row = pl * 8 + kk;
                float x0 = pp[kk * 3 + 0], x1 = pp[kk * 3 + 1], x2 = pp[kk * 3 + 2];
                float h = fmaf(x2, w1r2, fmaf(x1, w1r1, fmaf(x0, w1r0, b1v)));
                h = fmaxf(h, 0.01f * h);
                hw[row * 64 + (l ^ ((row & 7) << 3))] = (_Float16)h;
            }
        }

        // ---- layer2: A-frags from LDS, 8 MFMA ----
        f16x8 a[4];
        #pragma unroll
        for (int ks = 0; ks < 4; ++ks)
            a[ks] = *(const f16x8*)&hw[lr * 64 + (((ks * 2 + hi) ^ r7) << 3)];

        f32x16 acc0, acc1;
        #pragma unroll
        for (int q = 0; q < 16; ++q) { acc0[q] = 0.f; acc1[q] = 0.f; }
        #pragma unroll
        for (int ks = 0; ks < 4; ++ks) {
            acc0 = __builtin_amdgcn_mfma_f32_32x32x16_f16(a[ks], bfr[0][ks], acc0, 0, 0, 0);
            acc1 = __builtin_amdgcn_mfma_f32_32x32x16_f16(a[ks], bfr[1][ks], acc1, 0, 0, 0);
        }
        #pragma unroll
        for (int q = 0; q < 16; ++q) { acc0[q] += b2v0; acc1[q] += b2v1; }

        // ---- k-mix: redistribute so each lane owns one channel, full k ----
        float pfv[4];
        #pragma unroll
        for (int pl = 0; pl < 4; ++pl) {
            // per-half k-pairs: lane half hi holds k = 4*hi + {0..3}
            f16x2 x1 = pkrtz(acc0[pl * 4 + 0], acc0[pl * 4 + 1]);
            f16x2 x2 = pkrtz(acc0[pl * 4 + 2], acc0[pl * 4 + 3]);
            f16x2 y1 = pkrtz(acc1[pl * 4 + 0], acc1[pl * 4 + 1]);
            f16x2 y2 = pkrtz(acc1[pl * 4 + 2], acc1[pl * 4 + 3]);
            plswap(x1, y1);
            plswap(x2, y2);
            // after swap: lane's 4 regs = one set's kpairs; order depends on rot
            f16x2 k01 = rot ? y1 : x1;
            f16x2 k23 = rot ? y2 : x2;
            f16x2 k45 = rot ? x1 : y1;
            f16x2 k67 = rot ? x2 : y2;
            float f1[8];
            #pragma unroll
            for (int o = 0; o < 8; ++o) {
                float f = bk1v[o];
                f = __builtin_amdgcn_fdot2(k01, wk1p[o * 4 + 0], f, false);
                f = __builtin_amdgcn_fdot2(k23, wk1p[o * 4 + 1], f, false);
                f = __builtin_amdgcn_fdot2(k45, wk1p[o * 4 + 2], f, false);
                f = __builtin_amdgcn_fdot2(k67, wk1p[o * 4 + 3], f, false);
                f1[o] = fmaxf(f, 0.01f * f);
            }
            float pf = bk2v;
            #pragma unroll
            for (int j = 0; j < 4; ++j)
                pf = __builtin_amdgcn_fdot2(pkrtz(f1[2 * j], f1[2 * j + 1]), wk2p[j], pf, false);
            pfv[pl] = pf;
        }

        // ---- scatter: lane writes channel `chan` ----
        const int* pq = pts + (size_t)p0 * 3;
        #pragma unroll
        for (int pl = 0; pl < 4; ++pl) {
            if (p0 + pl < np) {
                int cell = (pq[pl * 3 + 0] * G + pq[pl * 3 + 1]) * G + pq[pl * 3 + 2];
                atomicAdd(&sums[(size_t)cell * 64 + chan], pfv[pl]);
                if (l == 0) atomicAdd(&cnt[cell], 1.0f);
            }
        }
    }
}

// ---------------------------------------------------------------------------
// Kernel 3: weight transform OIDHW fp32 -> fp16 B-fragment stream.
// ---------------------------------------------------------------------------
__global__ __launch_bounds__(256) void transform_w_fp16(
    const float* __restrict__ w, _Float16* __restrict__ wT)
{
    int o = blockIdx.x * 256 + threadIdx.x;
    if (o < 27 * 4 * 2 * 64 * 8) {
        int i   = o & 7;
        int l   = (o >> 3) & 63;
        int nf  = (o >> 9) & 1;
        int ks  = (o >> 10) & 3;
        int tap = o >> 12;
        int co = nf * 32 + (l & 31);
        int ci = ks * 16 + (l >> 5) * 8 + i;
        wT[o] = (_Float16)w[(co * 64 + ci) * 27 + tap];
    }
}

// ---------------------------------------------------------------------------
// Kernel 4: implicit-GEMM conv, LDS-staged 8x8x4 tile (halo 10x10x6, 76.8 KB
// -> 2 blocks/CU). 4 waves, wave = 1 z-plane, 2 mt x 2 nf. B streams from L2.
// CONV1: stage from fp32 sums normalized by cnt (mean fused); writes fp16
// dense. Else: stage fp16 dense; writes fp32 to d_out. Bounds-checked halo.
// ---------------------------------------------------------------------------
template<int CONV1>
__global__ __launch_bounds__(256, 2) void conv3d_mfma_s(
    const void* __restrict__ in_, const float* __restrict__ cntp,
    const _Float16* __restrict__ wT, const float* __restrict__ bias,
    void* __restrict__ out_)
{
    extern __shared__ ushort tile[];   // [600 voxels][64 ci] fp16, swizzled

    const int lb = blockIdx.x;
    const int bx = (lb & 7) * 128 + (lb >> 3);      // XCD-contiguous z-slabs
    const int X0 = (bx & 7) * 8, Y0 = ((bx >> 3) & 7) * 8, Z0 = (bx >> 6) * 4;
    const int tid = threadIdx.x;

    // ---- stage halo tile [hz 0..5][hy 0..9][hx 0..9] ----
    for (int c = tid; c < 4800; c += 256) {
        int vox = c >> 3, slot = c & 7;
        int hz = vox / 100, r0 = vox - hz * 100;
        int hy = r0 / 10, hx = r0 - hy * 10;
        int gz = Z0 + hz - 1, gy = Y0 + hy - 1, gx = X0 + hx - 1;
        int dst = vox * 64 + (((slot ^ hx) & 7) << 3);
        bool ok = ((unsigned)gz < 64u) && ((unsigned)gy < 64u) && ((unsigned)gx < 64u);
        if (CONV1) {
            f16x8 v;
            #pragma unroll
            for (int i = 0; i < 8; ++i) v[i] = (_Float16)0.f;
            if (ok) {
                int cell = (gz * 64 + gy) * 64 + gx;
                float cv = cntp[cell];
                float inv = (cv > 0.f) ? 1.f / cv : 0.f;
                const float4* p = (const float4*)((const float*)in_ +
                    ((size_t)cell * 64 + slot * 8));
                float4 a = p[0], b = p[1];
                v = f16x8{(_Float16)(a.x * inv), (_Float16)(a.y * inv),
                          (_Float16)(a.z * inv), (_Float16)(a.w * inv),
                          (_Float16)(b.x * inv), (_Float16)(b.y * inv),
                          (_Float16)(b.z * inv), (_Float16)(b.w * inv)};
            }
            *(f16x8*)&tile[dst] = v;
        } else {
            uint4 v = make_uint4(0u, 0u, 0u, 0u);
            if (ok) v = *(const uint4*)((const ushort*)in_ +
                    ((size_t)((gz * 64 + gy) * 64 + gx) * 64 + slot * 8));
            *(uint4*)&tile[dst] = v;
        }
    }
    __syncthreads();

    const int lane = tid & 63;
    const int wv   = tid >> 6;      // wave owns output plane z = Z0 + wv
    const int lr   = lane & 31;
    const int hi   = lane >> 5;

    int base_m[2];
    #pragma unroll
    for (int mt = 0; mt < 2; ++mt)
        base_m[mt] = wv * 100 + (mt * 4 + (lr >> 3)) * 10 + (lr & 7);

    f32x16 acc[2][2];
    #pragma unroll
    for (int mt = 0; mt < 2; ++mt)
        #pragma unroll
        for (int nf = 0; nf < 2; ++nf)
            #pragma unroll
            for (int q = 0; q < 16; ++q) acc[mt][nf][q] = 0.f;

    const f16x8* wTB = (const f16x8*)wT;

    #pragma unroll
    for (int dz = 0; dz < 3; ++dz)
    #pragma unroll
    for (int dy = 0; dy < 3; ++dy)
    #pragma unroll
    for (int dx = 0; dx < 3; ++dx) {
        const int tap = (dz * 3 + dy) * 3 + dx;
        const int rowoff = dz * 100 + dy * 10 + dx;
        const int sx = ((lr & 7) + dx) & 7;
        const f16x8* wB = wTB + tap * 512 + lane;
        f16x8 B0[4], B1[4];
        #pragma unroll
        for (int ks = 0; ks < 4; ++ks) {
            B0[ks] = wB[(ks * 2 + 0) * 64];
            B1[ks] = wB[(ks * 2 + 1) * 64];
        }
        #pragma unroll
        for (int ks = 0; ks < 4; ++ks) {
            const int sb = ((2 * ks + hi) ^ sx) & 7;
            #pragma unroll
            for (int mt = 0; mt < 2; ++mt) {
                int idx = (base_m[mt] + rowoff) * 64 + (sb << 3);
                f16x8 a = *(const f16x8*)&tile[idx];
                acc[mt][0] = __builtin_amdgcn_mfma_f32_32x32x16_f16(a, B0[ks], acc[mt][0], 0, 0, 0);
                acc[mt][1] = __builtin_amdgcn_mfma_f32_32x32x16_f16(a, B1[ks], acc[mt][1], 0, 0, 0);
            }
        }
    }

    // ---- epilogue: bias + relu ----
    const float bv0 = bias[lr], bv1 = bias[32 + lr];
    #pragma unroll
    for (int mt = 0; mt < 2; ++mt) {
        #pragma unroll
        for (int r = 0; r < 16; ++r) {
            int row = (r & 3) + 8 * (r >> 2) + 4 * hi;   // C/D: col=lane&31
            int vlw = mt * 32 + row;
            int gy = Y0 + (vlw >> 3), gx = X0 + (vlw & 7), gz = Z0 + wv;
            size_t off = (((size_t)(gz * 64 + gy) * 64 + gx) << 6) + lr;
            float v0 = fmaxf(acc[mt][0][r] + bv0, 0.f);
            float v1 = fmaxf(acc[mt][1][r] + bv1, 0.f);
            if (CONV1) {
                ((_Float16*)out_)[off]      = (_Float16)v0;
                ((_Float16*)out_)[off + 32] = (_Float16)v1;
            } else {
                ((float*)out_)[off]      = v0;
                ((float*)out_)[off + 32] = v1;
            }
        }
    }
}

// ---------------------------------------------------------------------------
extern "C" void kernel_launch(void* const* d_in, const int* in_sizes, int n_in,
                              void* d_out, int out_size, void* d_ws, size_t ws_size,
                              hipStream_t stream)
{
    const float* pos  = (const float*)d_in[0];
    const int*   pts  = (const int*)  d_in[1];
    const float* W1   = (const float*)d_in[2];
    const float* b1   = (const float*)d_in[3];
    const float* W2   = (const float*)d_in[4];
    const float* b2   = (const float*)d_in[5];
    const float* Wk1  = (const float*)d_in[6];
    const float* bk1  = (const float*)d_in[7];
    const float* Wk2  = (const float*)d_in[8];
    const float* bk2  = (const float*)d_in[9];
    const float* Cw1  = (const float*)d_in[10];
    const float* Cb1  = (const float*)d_in[11];
    const float* Cw2  = (const float*)d_in[12];
    const float* Cb2  = (const float*)d_in[13];

    float* out = (float*)d_out;                     // fp32 sums, then final out
    char*  ws  = (char*)d_ws;
    _Float16* c1d  = (_Float16*)ws;                 // [0, 32M): conv1 out fp16 dense
    float*    cntb = (float*)(ws + 33554432);       // 1 MB counts
    _Float16* wT1  = (_Float16*)(ws + 34603008);    // 221184 B
    _Float16* wT2  = (_Float16*)(ws + 34824192);    // 221184 B

    const int np = in_sizes[0] / 24;

    (void)hipMemsetAsync(out,  0, 67108864, stream);    // sums accumulate here
    (void)hipMemsetAsync(cntb, 0, 1048576, stream);

    transform_w_fp16<<<432, 256, 0, stream>>>(Cw1, wT1);
    transform_w_fp16<<<432, 256, 0, stream>>>(Cw2, wT2);

    const int nblk = 2048;
    point_mlp_scatter<<<nblk, 256, 0, stream>>>(
        pos, pts, W1, b1, W2, b2, Wk1, bk1, Wk2, bk2, out, cntb, np, nblk * 4);

    // conv1: sums (fp32, mean fused) -> c1d (fp16); conv2: c1d -> d_out (fp32)
    conv3d_mfma_s<1><<<1024, 256, 76800, stream>>>((const void*)out, cntb, wT1, Cb1, (void*)c1d);
    conv3d_mfma_s<0><<<1024, 256, 76800, stream>>>((const void*)c1d, nullptr, wT2, Cb2, (void*)out);
}